// Round 4
// baseline (326.331 us; speedup 1.0000x reference)
//
#include <hip/hip_runtime.h>
#include <math.h>

#define BB 8
#define NPTS 80000
#define KK 5
#define FF 20
#define GG 125           // blocks per batch -> 1000 blocks, exactly 10 tiles each
#define TILE 64
#define NTILES (NPTS / TILE)   // 1250, exact
#define JT (NTILES / GG)       // 10 tiles per block, exact
#define PSTRIDE 48             // partial row: 20 s1 + 20 s2 + 1 s0 + pad

// workspace layout (float offsets) -- small params/coefs only
#define WS_CM 0
#define WS_CV 800
#define WS_CP 1600
#define WS_A  1640
#define WS_D  1680
#define WS_E  2480

// ---- compute A/d/e from (means,var,pi) ----
__device__ __forceinline__ void make_coefs(const float* __restrict__ means,
                                           const float* __restrict__ var,
                                           const float* __restrict__ pi,
                                           float* __restrict__ A, float* __restrict__ D,
                                           float* __restrict__ E, int t) {
    if (t < BB * KK) {
        float sumlog = 0.f, summ2 = 0.f;
        for (int f = 0; f < FF; ++f) {
            float v = var[t * FF + f];
            float m = means[t * FF + f];
            float ic = 1.f / (v + 1e-6f);
            sumlog += logf(6.283185307179586f * v);
            summ2  += ic * m * m;
            D[t * FF + f] = ic * m;
            E[t * FF + f] = -0.5f * ic;
        }
        A[t] = logf(pi[t]) - 0.5f * sumlog - 0.5f * summ2;
    }
}

__global__ void prepare_kernel(const float* __restrict__ means, const float* __restrict__ var,
                               const float* __restrict__ pi, float* __restrict__ ws) {
    make_coefs(means, var, pi, ws + WS_A, ws + WS_D, ws + WS_E, (int)threadIdx.x);
}

// ---- E-step: per-wave cluster, per-lane point; double-buffered, 1 barrier/tile ----
template <bool WRITE_OUT>
__global__ __launch_bounds__(320) void estep_kernel(const float* __restrict__ data,
                                                    const float* __restrict__ ws,
                                                    float* __restrict__ partials,
                                                    float* __restrict__ out_ll,
                                                    float* __restrict__ out_post) {
    __shared__ float xs[2][FF][TILE + 1];   // transposed: conflict-free b32 reads
    __shared__ float lls[2][KK][TILE];

    const int b    = blockIdx.x / GG;
    const int g    = blockIdx.x % GG;
    const int tid  = threadIdx.x;
    const int w    = __builtin_amdgcn_readfirstlane(tid >> 6);   // cluster k
    const int lane = tid & 63;
    const int sp   = (tid * 4) / FF;     // staging point index
    const int sf   = (tid * 4) % FF;     // staging feature base (multiple of 4)

    const float Ak = (ws + WS_A)[b * KK + w];
    float dk[FF], ek[FF];                 // wave-uniform loads -> scalar regs
#pragma unroll
    for (int f = 0; f < FF; ++f) {
        dk[f] = (ws + WS_D)[(b * KK + w) * FF + f];
        ek[f] = (ws + WS_E)[(b * KK + w) * FF + f];
    }

    float s0 = 0.f, s1[FF], s2[FF];
    if (!WRITE_OUT) {
#pragma unroll
        for (int f = 0; f < FF; ++f) { s1[f] = 0.f; s2[f] = 0.f; }
    }

    const float* dbase = data + (size_t)b * NPTS * FF;
    // tile j (j=0..JT-1) has tile-id g + j*GG
    #define TPTR(j) ((const float4*)(dbase + (size_t)(g + (j) * GG) * TILE * FF))

    // prologue: stage tile 0, prefetch tiles 1 and 2
    float4 v0 = TPTR(0)[tid];
    float4 v  = TPTR(1)[tid];
    float4 v2 = TPTR(2)[tid];
    xs[0][sf][sp] = v0.x; xs[0][sf + 1][sp] = v0.y;
    xs[0][sf + 2][sp] = v0.z; xs[0][sf + 3][sp] = v0.w;
    __syncthreads();        // tile 0 staged

    int cur = 0;
    for (int j = 0; j < JT; ++j) {
        const int nxt = cur ^ 1;
        // stage tile j+1 into the other buffer (before this tile's barrier)
        if (j + 1 < JT) {
            xs[nxt][sf][sp] = v.x; xs[nxt][sf + 1][sp] = v.y;
            xs[nxt][sf + 2][sp] = v.z; xs[nxt][sf + 3][sp] = v.w;
        }
        v = v2;
        if (j + 3 < JT) v2 = TPTR(j + 3)[tid];

        // compute z for tile j from xs[cur]
        float x[FF];
        float z = Ak;
#pragma unroll
        for (int f = 0; f < FF; ++f) {
            x[f] = xs[cur][f][lane];
            z += x[f] * fmaf(ek[f], x[f], dk[f]);
        }
        lls[cur][w][lane] = z;
        __syncthreads();    // lls(j) complete AND xs[nxt] (tile j+1) staged

        float l0 = lls[cur][0][lane], l1 = lls[cur][1][lane], l2 = lls[cur][2][lane],
              l3 = lls[cur][3][lane], l4 = lls[cur][4][lane];
        float mx = fmaxf(fmaxf(fmaxf(l0, l1), fmaxf(l2, l3)), l4);
        float e0 = __expf(l0 - mx), e1 = __expf(l1 - mx), e2 = __expf(l2 - mx),
              e3 = __expf(l3 - mx), e4 = __expf(l4 - mx);
        float inv = 1.f / (e0 + e1 + e2 + e3 + e4);
        float ew  = (w == 0) ? e0 : (w == 1) ? e1 : (w == 2) ? e2 : (w == 3) ? e3 : e4;
        float post = ew * inv;

        if (WRITE_OUT) {
            size_t o = ((size_t)b * NPTS + (size_t)(g + j * GG) * TILE + lane) * KK + w;
            out_ll[o]   = z;
            out_post[o] = post;
        } else {
            s0 += post;
#pragma unroll
            for (int f = 0; f < FF; ++f) {
                float px = post * x[f];
                s1[f] += px;
                s2[f] += px * x[f];
            }
        }
        cur = nxt;
    }
    #undef TPTR

    if (!WRITE_OUT) {
#pragma unroll
        for (int off = 32; off > 0; off >>= 1) {
            s0 += __shfl_down(s0, off);
#pragma unroll
            for (int f = 0; f < FF; ++f) {
                s1[f] += __shfl_down(s1[f], off);
                s2[f] += __shfl_down(s2[f], off);
            }
        }
        if (lane == 0) {
            float* row = partials + ((size_t)(b * KK + w) * GG + g) * PSTRIDE;
#pragma unroll
            for (int f = 0; f < FF; ++f) { row[f] = s1[f]; row[FF + f] = s2[f]; }
            row[2 * FF] = s0;
        }
    }
}

// ---- reduce partials + M-step + next-iteration coefs, one block per batch ----
__global__ __launch_bounds__(320) void update_kernel(const float* __restrict__ partials,
                                                     float* __restrict__ ws,
                                                     float* __restrict__ om,
                                                     float* __restrict__ ov,
                                                     float* __restrict__ op,
                                                     int write_params) {
    __shared__ float s0s[KK];
    const int b    = blockIdx.x;
    const int tid  = threadIdx.x;
    const int w    = tid >> 6;
    const int lane = tid & 63;
    const int bk   = b * KK + w;

    // lane l sums partial slot l over all g (4 independent accumulators)
    float a0 = 0.f, a1 = 0.f, a2 = 0.f, a3 = 0.f;
    if (lane < PSTRIDE) {
        const float* base = partials + (size_t)bk * GG * PSTRIDE + lane;
        int gg = 0;
        for (; gg + 4 <= GG; gg += 4) {
            a0 += base[(size_t)(gg + 0) * PSTRIDE];
            a1 += base[(size_t)(gg + 1) * PSTRIDE];
            a2 += base[(size_t)(gg + 2) * PSTRIDE];
            a3 += base[(size_t)(gg + 3) * PSTRIDE];
        }
        for (; gg < GG; ++gg) a0 += base[(size_t)gg * PSTRIDE];
    }
    float sv = (a0 + a1) + (a2 + a3);

    float s0  = __shfl(sv, 2 * FF);          // cluster size
    float den = s0 + 1e-7f;
    float m   = sv / den;                    // lanes 0..19: mean[f]
    float s2f = __shfl(sv, FF + (lane % FF));
    float var = (s2f - 2.f * m * sv + m * m * s0) / den + 1e-6f;

    float* cm = ws + WS_CM; float* cv = ws + WS_CV; float* cp = ws + WS_CP;
    if (lane < FF) {
        cm[bk * FF + lane] = m;
        cv[bk * FF + lane] = var;
        if (write_params) { om[bk * FF + lane] = m; ov[bk * FF + lane] = var; }
    }

    if (lane == 0) s0s[w] = s0;
    __syncthreads();
    float tot = s0s[0] + s0s[1] + s0s[2] + s0s[3] + s0s[4];
    float pr  = (s0 / (float)NPTS) / fmaxf(tot / (float)NPTS, 1e-12f);
    if (lane == 0) {
        cp[bk] = pr;
        if (write_params) op[bk] = pr;
    }

    // coefs for next E-step in-register
    float ic = 1.f / (var + 1e-6f);
    if (lane < FF) {
        (ws + WS_D)[bk * FF + lane] = ic * m;
        (ws + WS_E)[bk * FF + lane] = -0.5f * ic;
    }
    float t1 = (lane < FF) ? logf(6.283185307179586f * var) : 0.f;
    float t2 = (lane < FF) ? ic * m * m : 0.f;
#pragma unroll
    for (int off = 1; off < 64; off <<= 1) {
        t1 += __shfl_xor(t1, off);
        t2 += __shfl_xor(t2, off);
    }
    if (lane == 0)
        (ws + WS_A)[bk] = logf(pr) - 0.5f * t1 - 0.5f * t2;
}

extern "C" void kernel_launch(void* const* d_in, const int* in_sizes, int n_in,
                              void* d_out, int out_size, void* d_ws, size_t ws_size,
                              hipStream_t stream) {
    const float* data     = (const float*)d_in[0];
    const float* in_means = (const float*)d_in[1];
    const float* in_var   = (const float*)d_in[2];
    const float* in_pi    = (const float*)d_in[3];
    float* ws  = (float*)d_ws;
    float* out = (float*)d_out;

    float* out_ll   = out;
    float* out_post = out + (size_t)BB * NPTS * KK;
    float* om       = out + 2 * (size_t)BB * NPTS * KK;
    float* ov       = om + BB * KK * FF;
    float* op       = ov + BB * KK * FF;

    // partials (960 KB) live in the not-yet-needed ll output region;
    // the final E-step fully overwrites it.
    float* partials = out_ll;

    prepare_kernel<<<1, 64, 0, stream>>>(in_means, in_var, in_pi, ws);

    for (int it = 0; it < 5; ++it) {
        estep_kernel<false><<<BB * GG, 320, 0, stream>>>(data, ws, partials,
                                                         nullptr, nullptr);
        update_kernel<<<BB, 320, 0, stream>>>(partials, ws, om, ov, op,
                                              (it == 4) ? 1 : 0);
    }
    estep_kernel<true><<<BB * GG, 320, 0, stream>>>(data, ws, nullptr,
                                                    out_ll, out_post);
}